// Round 3
// 477.697 us; speedup vs baseline: 1.0113x; 1.0113x over previous
//
#include <hip/hip_runtime.h>
#include <hip/hip_bf16.h>
#include <stdint.h>

// Problem shape (fixed by setup_inputs): x[8,2048,1024] fp32, W[4096,1024],
// b[4096], gA/lA[8,1024], gB/lB[4096,8]. out[8,2048,4096] fp32.
// M = 16384, K = 1024, N = 4096, R = 8, SCALE = 2.0.
//
// W_eff = W + 2*(gB@gA + lB@lA) (tiny), then out = x @ W_eff^T + b as one
// bf16-MFMA GEMM. 256^2 tile, ring-4 LDS, counted vmcnt (T4), XOR swizzle
// (T2), setprio (T5), XCD block swizzle (T1).
//
// Round-1 failure (absmax 76) attributed to: (1) nonzero `offset` arg of
// global_load_lds (untested semantics); (2) memory ops legally crossing the
// IntrNoMem raw s_barrier. Fixed here: staging offsets via pointer
// arithmetic only (offset=0, round-0-proven), every barrier fenced with asm
// memory clobbers, proven 2-barrier-per-step skeleton.
// Round-2 was an infra failure (container died during push; no kernel
// signal) — this is the same kernel resubmitted unchanged.

#define M_DIM 16384
#define N_DIM 4096
#define K_DIM 1024
#define R_DIM 8
#define LORA_SCALE 2.0f

typedef __attribute__((ext_vector_type(4))) float  f32x4;
typedef __attribute__((ext_vector_type(8))) __bf16 bf16x8;
typedef __attribute__((ext_vector_type(4))) unsigned short u16x4;
typedef __attribute__((ext_vector_type(8))) unsigned short u16x8;

__device__ __forceinline__ unsigned short f2bf(float f) {
  union { float f; uint32_t u; } v; v.f = f;
  uint32_t u = v.u;
  return (unsigned short)((u + 0x7fffu + ((u >> 16) & 1u)) >> 16);
}

// ---------------- prep 1: x fp32 -> bf16 ----------------
__global__ void cvt_x_kernel(const float* __restrict__ x,
                             unsigned short* __restrict__ xb) {
  long i = ((long)blockIdx.x * blockDim.x + threadIdx.x) * 8;
  f32x4 a = *(const f32x4*)(x + i);
  f32x4 b = *(const f32x4*)(x + i + 4);
  u16x8 o;
  o[0] = f2bf(a[0]); o[1] = f2bf(a[1]); o[2] = f2bf(a[2]); o[3] = f2bf(a[3]);
  o[4] = f2bf(b[0]); o[5] = f2bf(b[1]); o[6] = f2bf(b[2]); o[7] = f2bf(b[3]);
  *(u16x8*)(xb + i) = o;
}

// ---------------- prep 2: W_eff = W + 2*(gB@gA + lB@lA) -> bf16 ----------------
__global__ void weff_kernel(const float* __restrict__ W,
                            const float* __restrict__ gA,
                            const float* __restrict__ gB,
                            const float* __restrict__ lA,
                            const float* __restrict__ lB,
                            unsigned short* __restrict__ Wb) {
  int idx = blockIdx.x * blockDim.x + threadIdx.x;   // over N*K/4
  int o  = idx >> 8;            // K/4 = 256
  int i4 = (idx & 255) << 2;
  f32x4 w = *(const f32x4*)(W + ((long)o << 10) + i4);
#pragma unroll
  for (int r = 0; r < R_DIM; ++r) {
    float cg = LORA_SCALE * gB[o * R_DIM + r];
    float cl = LORA_SCALE * lB[o * R_DIM + r];
    f32x4 ga = *(const f32x4*)(gA + (r << 10) + i4);
    f32x4 la = *(const f32x4*)(lA + (r << 10) + i4);
    w += cg * ga + cl * la;
  }
  u16x4 out;
  out[0] = f2bf(w[0]); out[1] = f2bf(w[1]); out[2] = f2bf(w[2]); out[3] = f2bf(w[3]);
  *(u16x4*)(Wb + (long)idx * 4) = out;
}

// ---------------- GEMM: C[M][N] = Xb[M][K] @ Wb[N][K]^T + bias ----------------
// 256x256 tile, BK=32, 512 threads (8 waves: 2M x 4N), ring-4 LDS buffers,
// counted vmcnt(8), XOR-swizzled LDS, setprio, 2 fenced barriers per step.
//
// LDS (ushorts): A ring [0, 32768): 4 bufs x (256 rows x 32);
//                B ring [32768, 65536): same. 128 KiB total.
// Swizzle: LDS slot (row, s) holds global k-chunk g = s ^ ((row>>1)&3)
// (chunks of 8 bf16). Staging pre-swizzles the GLOBAL source address (LDS
// dest stays linear, required by global_load_lds); reads apply the same XOR.
// Bank check (ds_read_b128): start bank = (lr&1)<<4 | (lq^((lr>>1)&3))<<2
// -> 8 lanes per 4-bank window, all 32 banks busy -> conflict-free floor.

#define GL16(g, l)                                                     \
  __builtin_amdgcn_global_load_lds(                                    \
      (const __attribute__((address_space(1))) void*)(g),              \
      (__attribute__((address_space(3))) void*)(l), 16, 0, 0)

// Barrier fenced with compiler memory clobbers: llvm.amdgcn.s.barrier is
// IntrNoMem, so without the fences LLVM may move LDS/DMA ops across it.
#define BAR() do {                         \
    asm volatile("" ::: "memory");         \
    __builtin_amdgcn_s_barrier();          \
    asm volatile("" ::: "memory");         \
  } while (0)

__global__ __launch_bounds__(512, 2)
void gemm_bias_kernel(const unsigned short* __restrict__ A,   // [M][K] bf16
                      const unsigned short* __restrict__ B,   // [N][K] bf16
                      const float* __restrict__ bias,         // [N]
                      float* __restrict__ C) {                // [M][N]
  __shared__ __align__(16) unsigned short lds[65536];  // 128 KiB

  const int tid  = threadIdx.x;
  const int wave = tid >> 6;
  const int lane = tid & 63;
  const int wm = wave >> 2;            // 0..1   wave row (128 rows)
  const int wn = wave & 3;             // 0..3   wave col (64 cols)
  const int lr = lane & 15;
  const int lq = lane >> 4;

  // T1: XCD-aware bijective block swizzle (1024 = 8 * 128)
  const int bid = (int)blockIdx.x;
  const int swz = ((bid & 7) << 7) | (bid >> 3);
  const int by = swz >> 4;             // 0..63  M-block
  const int bx = swz & 15;             // 0..15  N-block
  const long m0 = (long)by << 8;
  const long n0 = (long)bx << 8;

  // ---- staging (pre-swizzled global source, linear LDS dest) ----
  // chunk lidx in 0..1023 covers LDS ushorts [lidx*8, lidx*8+8):
  //   row = lidx>>2, slot s = lidx&3, global chunk g = s ^ ((row>>1)&3)
  const int l0 = tid, l1 = tid + 512;
  const int r0 = l0 >> 2, g0 = (l0 & 3) ^ ((r0 >> 1) & 3);
  const int r1 = l1 >> 2, g1 = (l1 & 3) ^ ((r1 >> 1) & 3);
  const unsigned short* ga0 = A + (m0 + r0) * K_DIM + g0 * 8;
  const unsigned short* ga1 = A + (m0 + r1) * K_DIM + g1 * 8;
  const unsigned short* gb0 = B + (n0 + r0) * K_DIM + g0 * 8;
  const unsigned short* gb1 = B + (n0 + r1) * K_DIM + g1 * 8;
  unsigned short* sa0 = lds + l0 * 8;
  unsigned short* sa1 = lds + l1 * 8;
  unsigned short* sb0 = lds + 32768 + l0 * 8;
  unsigned short* sb1 = lds + 32768 + l1 * 8;

  // ---- ds_read bases (same XOR; (row>>1)&3 == (lr>>1)&3 because wm*128,
  //      wn*64, i*16 all vanish mod 4 after >>1) ----
  const int sw = (lq ^ ((lr >> 1) & 3)) * 8;
  const unsigned short* pa = lds + (wm * 128 + lr) * 32 + sw;
  const unsigned short* pb = lds + 32768 + (wn * 64 + lr) * 32 + sw;

  f32x4 acc[8][4] = {};

  // TOFF is in ushorts (tile t -> t*32); offsets folded by the compiler
  // into the instruction with its true semantics (round-0-proven path).
#define STAGE(BUF, TOFF) do {                       \
    GL16(ga0 + (TOFF), sa0 + (BUF) * 8192);         \
    GL16(ga1 + (TOFF), sa1 + (BUF) * 8192);         \
    GL16(gb0 + (TOFF), sb0 + (BUF) * 8192);         \
    GL16(gb1 + (TOFF), sb1 + (BUF) * 8192);         \
  } while (0)

  // prologue: stage K-tiles 0,1,2 (12 loads in flight per thread)
  STAGE(0, 0);
  STAGE(1, 32);
  STAGE(2, 64);

  // Step U (tile t=4*mi+U, buf U): own tile resident via counted vmcnt,
  // barrier1 joins all waves (cross-wave residency; buf (U-1)&3 free since
  // its readers retired at step U-1's barrier2), prefetch tile t+3 into
  // buf (U-1)&3, ds_read frags, MFMA, barrier2 (retires this step's reads
  // before anyone re-stages buf U at step U+1).
#define TSTEP(U, DOSTAGE, VMC) do {                                     \
    asm volatile("s_waitcnt vmcnt(" #VMC ")" ::: "memory");             \
    BAR();                                                              \
    if (DOSTAGE) STAGE(((U) + 3) & 3, ((U) + 3) * 32);                  \
    bf16x8 af[8], bfr[4];                                               \
    _Pragma("unroll")                                                   \
    for (int i = 0; i < 8; ++i)                                         \
      af[i] = *(const bf16x8*)(pa + (U) * 8192 + i * 512);              \
    _Pragma("unroll")                                                   \
    for (int j = 0; j < 4; ++j)                                         \
      bfr[j] = *(const bf16x8*)(pb + (U) * 8192 + j * 512);             \
    __builtin_amdgcn_s_setprio(1);                                      \
    _Pragma("unroll")                                                   \
    for (int i = 0; i < 8; ++i)                                         \
      _Pragma("unroll")                                                 \
      for (int j = 0; j < 4; ++j)                                       \
        acc[i][j] = __builtin_amdgcn_mfma_f32_16x16x32_bf16(            \
            af[i], bfr[j], acc[i][j], 0, 0, 0);                         \
    __builtin_amdgcn_s_setprio(0);                                      \
    BAR();                                                              \
  } while (0)

  // main: 7 macro-iters x 4 tiles (tiles 0..27), ptrs advance 4 tiles/iter
  for (int mi = 0; mi < 7; ++mi) {
    TSTEP(0, 1, 8);
    TSTEP(1, 1, 8);
    TSTEP(2, 1, 8);
    TSTEP(3, 1, 8);
    ga0 += 128; ga1 += 128; gb0 += 128; gb1 += 128;
  }
  // tail: tiles 28..31 (ptrs at tile 28). Stage 31 at step 28; then drain.
  TSTEP(0, 1, 8);   // t=28: wait 28; stage 31 (outstanding 29,30,31)
  TSTEP(1, 0, 8);   // t=29: wait 29 (outstanding 30,31)
  TSTEP(2, 0, 4);   // t=30: wait 30 (outstanding 31)
  TSTEP(3, 0, 0);   // t=31: drain

#undef TSTEP
#undef STAGE

  // epilogue: C[m0 + wm*128 + i*16 + lq*4 + rg][n0 + wn*64 + j*16 + lr]
  const int crow = (int)m0 + wm * 128 + lq * 4;
  const int ccol = (int)n0 + wn * 64 + lr;
#pragma unroll
  for (int j = 0; j < 4; ++j) {
    const int col = ccol + j * 16;
    const float bv = bias[col];
#pragma unroll
    for (int i = 0; i < 8; ++i) {
      const long base = (long)(crow + i * 16) * N_DIM + col;
#pragma unroll
      for (int rg = 0; rg < 4; ++rg)
        C[base + (long)rg * N_DIM] = acc[i][j][rg] + bv;
    }
  }
}

extern "C" void kernel_launch(void* const* d_in, const int* in_sizes, int n_in,
                              void* d_out, int out_size, void* d_ws, size_t ws_size,
                              hipStream_t stream) {
  const float* x  = (const float*)d_in[0];
  const float* W  = (const float*)d_in[1];
  const float* b  = (const float*)d_in[2];
  const float* gA = (const float*)d_in[3];
  const float* gB = (const float*)d_in[4];
  const float* lA = (const float*)d_in[5];
  const float* lB = (const float*)d_in[6];
  float* out = (float*)d_out;

  unsigned short* xb = (unsigned short*)d_ws;                       // 33.5 MB
  unsigned short* Wb = xb + (long)M_DIM * K_DIM;                    // 8.4 MB

  // x -> bf16: 16777216 elems / 8 per thread
  cvt_x_kernel<<<8192, 256, 0, stream>>>(x, xb);
  // W_eff: 4096*1024/4 threads
  weff_kernel<<<4096, 256, 0, stream>>>(W, gA, gB, lA, lB, Wb);
  // GEMM: 1024 blocks (16 N-blocks x 64 M-blocks), 512 threads
  gemm_bias_kernel<<<1024, 512, 0, stream>>>(xb, Wb, b, out);
}

// Round 4
// 472.364 us; speedup vs baseline: 1.0227x; 1.0113x over previous
//
#include <hip/hip_runtime.h>
#include <hip/hip_bf16.h>
#include <stdint.h>

// Problem shape: x[8,2048,1024] fp32, W[4096,1024], b[4096], gA/lA[8,1024],
// gB/lB[4096,8]. out[8,2048,4096] fp32. M=16384, K=1024, N=4096, SCALE=2.
//
// W_eff = W + 2*(gB@gA + lB@lA), then out = x @ W_eff^T + b as one bf16 MFMA
// GEMM. 256^2 tile, ring-4 LDS (BK=32), counted vmcnt (T4), XOR swizzle (T2),
// setprio (T5), XCD block swizzle (T1) — all harness-verified in round 3
// (passed, gemm ~175 us). Round 3 was still a COARSE schedule (reads then
// MFMAs between one barrier pair) — the regime where T2/T5 are null.
// This round adds T3: each K-step split into 4 barrier-pair phases
// ({ds_read subtile + 1 stage} -> bar -> 8 MFMA -> bar), m201's shape.
// Index math, staging addresses, vmcnt ledger, epilogue: unchanged.

#define M_DIM 16384
#define N_DIM 4096
#define K_DIM 1024
#define R_DIM 8
#define LORA_SCALE 2.0f

typedef __attribute__((ext_vector_type(4))) float  f32x4;
typedef __attribute__((ext_vector_type(8))) __bf16 bf16x8;
typedef __attribute__((ext_vector_type(4))) unsigned short u16x4;
typedef __attribute__((ext_vector_type(8))) unsigned short u16x8;

__device__ __forceinline__ unsigned short f2bf(float f) {
  union { float f; uint32_t u; } v; v.f = f;
  uint32_t u = v.u;
  return (unsigned short)((u + 0x7fffu + ((u >> 16) & 1u)) >> 16);
}

// ---------------- prep 1: x fp32 -> bf16 ----------------
__global__ void cvt_x_kernel(const float* __restrict__ x,
                             unsigned short* __restrict__ xb) {
  long i = ((long)blockIdx.x * blockDim.x + threadIdx.x) * 8;
  f32x4 a = *(const f32x4*)(x + i);
  f32x4 b = *(const f32x4*)(x + i + 4);
  u16x8 o;
  o[0] = f2bf(a[0]); o[1] = f2bf(a[1]); o[2] = f2bf(a[2]); o[3] = f2bf(a[3]);
  o[4] = f2bf(b[0]); o[5] = f2bf(b[1]); o[6] = f2bf(b[2]); o[7] = f2bf(b[3]);
  *(u16x8*)(xb + i) = o;
}

// ---------------- prep 2: W_eff = W + 2*(gB@gA + lB@lA) -> bf16 ----------------
__global__ void weff_kernel(const float* __restrict__ W,
                            const float* __restrict__ gA,
                            const float* __restrict__ gB,
                            const float* __restrict__ lA,
                            const float* __restrict__ lB,
                            unsigned short* __restrict__ Wb) {
  int idx = blockIdx.x * blockDim.x + threadIdx.x;   // over N*K/4
  int o  = idx >> 8;            // K/4 = 256
  int i4 = (idx & 255) << 2;
  f32x4 w = *(const f32x4*)(W + ((long)o << 10) + i4);
#pragma unroll
  for (int r = 0; r < R_DIM; ++r) {
    float cg = LORA_SCALE * gB[o * R_DIM + r];
    float cl = LORA_SCALE * lB[o * R_DIM + r];
    f32x4 ga = *(const f32x4*)(gA + (r << 10) + i4);
    f32x4 la = *(const f32x4*)(lA + (r << 10) + i4);
    w += cg * ga + cl * la;
  }
  u16x4 out;
  out[0] = f2bf(w[0]); out[1] = f2bf(w[1]); out[2] = f2bf(w[2]); out[3] = f2bf(w[3]);
  *(u16x4*)(Wb + (long)idx * 4) = out;
}

// ---------------- GEMM: C[M][N] = Xb[M][K] @ Wb[N][K]^T + bias ----------------
// 256x256 tile, BK=32, 512 threads (8 waves: 2M x 4N), ring-4 LDS buffers.
// LDS (ushorts): A ring [0, 32768): 4 bufs x (256 rows x 32);
//                B ring [32768, 65536): same. 128 KiB total.
// Swizzle: LDS slot (row, s) holds global k-chunk g = s ^ ((row>>1)&3)
// (chunks of 8 bf16). Staging pre-swizzles the GLOBAL source address (LDS
// dest stays linear, required by global_load_lds); reads apply the same XOR.
// Bank check (ds_read_b128): start bank = (lr&1)<<4 | (lq^((lr>>1)&3))<<2
// -> conflict-free floor.  All harness-verified (round 3, absmax 0.031).

#define GL16(g, l)                                                     \
  __builtin_amdgcn_global_load_lds(                                    \
      (const __attribute__((address_space(1))) void*)(g),              \
      (__attribute__((address_space(3))) void*)(l), 16, 0, 0)

// Barrier fenced with compiler memory clobbers: llvm.amdgcn.s.barrier is
// IntrNoMem; fences keep LDS/DMA ops on the right side.
#define BAR() do {                         \
    asm volatile("" ::: "memory");         \
    __builtin_amdgcn_s_barrier();          \
    asm volatile("" ::: "memory");         \
  } while (0)

__global__ __launch_bounds__(512, 2)
void gemm_bias_kernel(const unsigned short* __restrict__ A,   // [M][K] bf16
                      const unsigned short* __restrict__ B,   // [N][K] bf16
                      const float* __restrict__ bias,         // [N]
                      float* __restrict__ C) {                // [M][N]
  __shared__ __align__(16) unsigned short lds[65536];  // 128 KiB

  const int tid  = threadIdx.x;
  const int wave = tid >> 6;
  const int lane = tid & 63;
  const int wm = wave >> 2;            // 0..1   wave row (128 rows)
  const int wn = wave & 3;             // 0..3   wave col (64 cols)
  const int lr = lane & 15;
  const int lq = lane >> 4;

  // T1: XCD-aware bijective block swizzle (1024 = 8 * 128)
  const int bid = (int)blockIdx.x;
  const int swz = ((bid & 7) << 7) | (bid >> 3);
  const int by = swz >> 4;             // 0..63  M-block
  const int bx = swz & 15;             // 0..15  N-block
  const long m0 = (long)by << 8;
  const long n0 = (long)bx << 8;

  // ---- staging (pre-swizzled global source, linear LDS dest) ----
  // chunk lidx in 0..1023 covers LDS ushorts [lidx*8, lidx*8+8):
  //   row = lidx>>2, slot s = lidx&3, global chunk g = s ^ ((row>>1)&3)
  const int l0 = tid, l1 = tid + 512;
  const int r0 = l0 >> 2, g0 = (l0 & 3) ^ ((r0 >> 1) & 3);
  const int r1 = l1 >> 2, g1 = (l1 & 3) ^ ((r1 >> 1) & 3);
  const unsigned short* ga0 = A + (m0 + r0) * K_DIM + g0 * 8;
  const unsigned short* ga1 = A + (m0 + r1) * K_DIM + g1 * 8;
  const unsigned short* gb0 = B + (n0 + r0) * K_DIM + g0 * 8;
  const unsigned short* gb1 = B + (n0 + r1) * K_DIM + g1 * 8;
  unsigned short* sa0 = lds + l0 * 8;
  unsigned short* sa1 = lds + l1 * 8;
  unsigned short* sb0 = lds + 32768 + l0 * 8;
  unsigned short* sb1 = lds + 32768 + l1 * 8;

  // ---- ds_read bases (same XOR; (row>>1)&3 == (lr>>1)&3 because wm*128,
  //      wn*64, i*16 all vanish mod 4 after >>1) ----
  const int sw = (lq ^ ((lr >> 1) & 3)) * 8;
  const unsigned short* pa = lds + (wm * 128 + lr) * 32 + sw;
  const unsigned short* pb = lds + 32768 + (wn * 64 + lr) * 32 + sw;

  f32x4 acc[8][4] = {};

  // prologue staging (one whole tile per STAGE; TOFF in ushorts)
#define STAGE(BUF, TOFF) do {                       \
    GL16(ga0 + (TOFF), sa0 + (BUF) * 8192);         \
    GL16(ga1 + (TOFF), sa1 + (BUF) * 8192);         \
    GL16(gb0 + (TOFF), sb0 + (BUF) * 8192);         \
    GL16(gb1 + (TOFF), sb1 + (BUF) * 8192);         \
  } while (0)

  STAGE(0, 0);     // tiles 0,1,2 in flight (12 loads/thread)
  STAGE(1, 32);
  STAGE(2, 64);

  // T3 phase: {ds_read A-pair (+B quad in phase 0, hoisted into TSTEP) +
  // one next-tile stage} -> bar -> setprio(1) 8 MFMA setprio(0) -> bar.
#define PH(U, I0, STGSTMT) do {                                         \
    bf16x8 a0 = *(const bf16x8*)(pa + (U) * 8192 + (I0) * 512);         \
    bf16x8 a1 = *(const bf16x8*)(pa + (U) * 8192 + ((I0) + 1) * 512);   \
    STGSTMT;                                                            \
    BAR();                                                              \
    __builtin_amdgcn_s_setprio(1);                                      \
    _Pragma("unroll")                                                   \
    for (int j = 0; j < 4; ++j) {                                       \
      acc[(I0)][j]     = __builtin_amdgcn_mfma_f32_16x16x32_bf16(       \
          a0, bfr[j], acc[(I0)][j], 0, 0, 0);                           \
      acc[(I0) + 1][j] = __builtin_amdgcn_mfma_f32_16x16x32_bf16(       \
          a1, bfr[j], acc[(I0) + 1][j], 0, 0, 0);                       \
    }                                                                   \
    __builtin_amdgcn_s_setprio(0);                                      \
    BAR();                                                              \
  } while (0)

  // Step U (tile t, buf U&3): vmcnt(VMC) -> own tile resident; opening
  // barrier -> cross-wave residency AND retires buf (U-1)&3's readers
  // (their last lgkm-wait precedes their arrival here), so the per-phase
  // stages into buf (U+3)&3 = (U-1)&3 are WAR-safe.
#define TSTEP(U, DOSTAGE, VMC) do {                                       \
    asm volatile("s_waitcnt vmcnt(" #VMC ")" ::: "memory");               \
    BAR();                                                                \
    bf16x8 bfr[4];                                                        \
    _Pragma("unroll")                                                     \
    for (int j = 0; j < 4; ++j)                                           \
      bfr[j] = *(const bf16x8*)(pb + (U) * 8192 + j * 512);               \
    PH(U, 0, if (DOSTAGE) GL16(ga0 + ((U) + 3) * 32,                      \
                               sa0 + (((U) + 3) & 3) * 8192));            \
    PH(U, 2, if (DOSTAGE) GL16(ga1 + ((U) + 3) * 32,                      \
                               sa1 + (((U) + 3) & 3) * 8192));            \
    PH(U, 4, if (DOSTAGE) GL16(gb0 + ((U) + 3) * 32,                      \
                               sb0 + (((U) + 3) & 3) * 8192));            \
    PH(U, 6, if (DOSTAGE) GL16(gb1 + ((U) + 3) * 32,                      \
                               sb1 + (((U) + 3) & 3) * 8192));            \
  } while (0)

  // main: 7 macro-iters x 4 tiles (tiles 0..27), ptrs advance 4 tiles/iter
  for (int mi = 0; mi < 7; ++mi) {
    TSTEP(0, 1, 8);
    TSTEP(1, 1, 8);
    TSTEP(2, 1, 8);
    TSTEP(3, 1, 8);
    ga0 += 128; ga1 += 128; gb0 += 128; gb1 += 128;
  }
  // tail: tiles 28..31 (ptrs at tile 28). Stage 31 during step 28; drain.
  TSTEP(0, 1, 8);   // t=28: wait 28 (12 out -> 8); stage 31 per-phase
  TSTEP(1, 0, 8);   // t=29: 12 out -> 8 (tile 29 done)
  TSTEP(2, 0, 4);   // t=30: 8 out -> 4
  TSTEP(3, 0, 0);   // t=31: drain

#undef TSTEP
#undef PH
#undef STAGE

  // epilogue: C[m0 + wm*128 + i*16 + lq*4 + rg][n0 + wn*64 + j*16 + lr]
  const int crow = (int)m0 + wm * 128 + lq * 4;
  const int ccol = (int)n0 + wn * 64 + lr;
#pragma unroll
  for (int j = 0; j < 4; ++j) {
    const int col = ccol + j * 16;
    const float bv = bias[col];
#pragma unroll
    for (int i = 0; i < 8; ++i) {
      const long base = (long)(crow + i * 16) * N_DIM + col;
#pragma unroll
      for (int rg = 0; rg < 4; ++rg)
        C[base + (long)rg * N_DIM] = acc[i][j][rg] + bv;
    }
  }
}

extern "C" void kernel_launch(void* const* d_in, const int* in_sizes, int n_in,
                              void* d_out, int out_size, void* d_ws, size_t ws_size,
                              hipStream_t stream) {
  const float* x  = (const float*)d_in[0];
  const float* W  = (const float*)d_in[1];
  const float* b  = (const float*)d_in[2];
  const float* gA = (const float*)d_in[3];
  const float* gB = (const float*)d_in[4];
  const float* lA = (const float*)d_in[5];
  const float* lB = (const float*)d_in[6];
  float* out = (float*)d_out;

  unsigned short* xb = (unsigned short*)d_ws;                       // 33.5 MB
  unsigned short* Wb = xb + (long)M_DIM * K_DIM;                    // 8.4 MB

  // x -> bf16: 16777216 elems / 8 per thread
  cvt_x_kernel<<<8192, 256, 0, stream>>>(x, xb);
  // W_eff: 4096*1024/4 threads
  weff_kernel<<<4096, 256, 0, stream>>>(W, gA, gB, lA, lB, Wb);
  // GEMM: 1024 blocks (16 N-blocks x 64 M-blocks), 512 threads
  gemm_bias_kernel<<<1024, 512, 0, stream>>>(xb, Wb, b, out);
}